// Round 3
// baseline (78.397 us; speedup 1.0000x reference)
//
#include <hip/hip_runtime.h>

// Gemma4VisionPooler: B=16, S=4096 (64x64 grid), H=1152, OUT=256, k=4.
// out[b,o,:] = (sum over the <=16 rows x[b,s,:] with bucket(s)==o) * sqrt(H)/16
// bucket = (px/k) + (max_x/k)*(py/k); pos clamped >=0; padding rows ([-1,-1]) skipped.

#define BB 16
#define SS 4096
#define HH 1152
#define OUTL 256
#define KK 4
#define K2 16
#define H4 (HH / 4)     // 288 float4 per row
#define C4 (H4 / 4)     // 72 threads per output row, 4 float4 each (rep-strided)

// ---- Fused prologue: single register-cached pass; sorted bucket lists ----
__global__ __launch_bounds__(256) void build_fused(const int* __restrict__ pos,
                                                   int* __restrict__ counts,
                                                   int* __restrict__ rows) {
    int b = blockIdx.x;
    int t = threadIdx.x;
    const int2* p2 = reinterpret_cast<const int2*>(pos) + (size_t)b * SS;

    // one global pass: cache this thread's 16 positions in registers
    int2 r[SS / 256];
#pragma unroll
    for (int i = 0; i < SS / 256; ++i) r[i] = p2[t + i * 256];

    // max px (padding px=-1 never beats init 0)
    int m = 0;
#pragma unroll
    for (int i = 0; i < SS / 256; ++i) m = max(m, r[i].x);
    __shared__ int red[256];
    red[t] = m;
    __syncthreads();
    for (int w = 128; w > 0; w >>= 1) {
        if (t < w) red[t] = max(red[t], red[t + w]);
        __syncthreads();
    }
    __shared__ int smxk;
    if (t == 0) smxk = (red[0] + 1) / KK;

    __shared__ int lcnt[OUTL];
    __shared__ int lrows[OUTL * K2];
    lcnt[t] = 0;
    __syncthreads();
    int mxk = smxk;
#pragma unroll
    for (int i = 0; i < SS / 256; ++i) {
        int2 xy = r[i];
        if (xy.x == -1 && xy.y == -1) continue;  // padding row
        int px = max(xy.x, 0), py = max(xy.y, 0);
        int kidx = px / KK + mxk * (py / KK);
        if ((unsigned)kidx < OUTL) {
            int slot = atomicAdd(&lcnt[kidx], 1);
            if (slot < K2) lrows[kidx * K2 + slot] = t + i * 256;
        }
    }
    __syncthreads();

    // thread t owns bucket t: sort its list ascending (monotone read streams),
    // then write out.
    int cnt = min(lcnt[t], K2);
    int v[K2];
    for (int j = 0; j < cnt; ++j) {
        int key = lrows[t * K2 + j];
        int p = j;
        while (p > 0 && v[p - 1] > key) { v[p] = v[p - 1]; --p; }
        v[p] = key;
    }
    counts[b * OUTL + t] = cnt;
    int* rb = rows + ((size_t)b * OUTL + t) * K2;
    for (int j = 0; j < cnt; ++j) rb[j] = v[j];
}

// ---- Heavy gather: 4 rep-strided float4 (64 B) per thread ----
__global__ __launch_bounds__(256) void gather_kernel(const float* __restrict__ x,
                                                     const int* __restrict__ counts,
                                                     const int* __restrict__ rows,
                                                     float* __restrict__ out) {
    int idx = blockIdx.x * 256 + threadIdx.x;  // [0, B*OUT*C4)
    int c4 = idx % C4;
    int bo = idx / C4;            // b*OUT + o
    int b = bo >> 8;

    // rep-strided columns: rep r covers col = c4 + r*C4 -> every load/store
    // instruction is wave-contiguous.
    const float4* xb = reinterpret_cast<const float4*>(x) + (size_t)b * SS * H4 + c4;
    const int* rl = rows + (size_t)bo * K2;
    int cnt = min(counts[bo], K2);

    float4 a0 = {0,0,0,0}, a1 = {0,0,0,0}, a2 = {0,0,0,0}, a3 = {0,0,0,0};
    if (cnt == K2) {
        const int4* rl4 = reinterpret_cast<const int4*>(rl);
        int4 ra = rl4[0], rb_ = rl4[1], rc = rl4[2], rd = rl4[3];
        int ridx[K2] = {ra.x, ra.y, ra.z, ra.w, rb_.x, rb_.y, rb_.z, rb_.w,
                        rc.x, rc.y, rc.z, rc.w, rd.x, rd.y, rd.z, rd.w};
#pragma unroll
        for (int j = 0; j < K2; ++j) {
            const float4* p = xb + (size_t)ridx[j] * H4;
            float4 v0 = p[0], v1 = p[C4], v2 = p[2 * C4], v3 = p[3 * C4];
            a0.x += v0.x; a0.y += v0.y; a0.z += v0.z; a0.w += v0.w;
            a1.x += v1.x; a1.y += v1.y; a1.z += v1.z; a1.w += v1.w;
            a2.x += v2.x; a2.y += v2.y; a2.z += v2.z; a2.w += v2.w;
            a3.x += v3.x; a3.y += v3.y; a3.z += v3.z; a3.w += v3.w;
        }
    } else {
        for (int j = 0; j < cnt; ++j) {
            const float4* p = xb + (size_t)rl[j] * H4;
            float4 v0 = p[0], v1 = p[C4], v2 = p[2 * C4], v3 = p[3 * C4];
            a0.x += v0.x; a0.y += v0.y; a0.z += v0.z; a0.w += v0.w;
            a1.x += v1.x; a1.y += v1.y; a1.z += v1.z; a1.w += v1.w;
            a2.x += v2.x; a2.y += v2.y; a2.z += v2.z; a2.w += v2.w;
            a3.x += v3.x; a3.y += v3.y; a3.z += v3.z; a3.w += v3.w;
        }
    }
    const float scale = 2.1213203435596424f;  // sqrt(1152)/16
    float4* ob = reinterpret_cast<float4*>(out) + (size_t)bo * H4 + c4;
#define SC(a) { a.x *= scale; a.y *= scale; a.z *= scale; a.w *= scale; }
    SC(a0) SC(a1) SC(a2) SC(a3)
#undef SC
    ob[0] = a0; ob[C4] = a1; ob[2 * C4] = a2; ob[3 * C4] = a3;
}

extern "C" void kernel_launch(void* const* d_in, const int* in_sizes, int n_in,
                              void* d_out, int out_size, void* d_ws, size_t ws_size,
                              hipStream_t stream) {
    const float* x = (const float*)d_in[0];
    const int* pos = (const int*)d_in[1];
    float* out = (float*)d_out;

    // ws: counts [B*OUT] ints, rows [B*OUT*K2] ints
    int* counts = (int*)d_ws;
    int* rows = counts + BB * OUTL;

    build_fused<<<BB, 256, 0, stream>>>(pos, counts, rows);

    int total = BB * OUTL * C4;     // 294,912 threads
    gather_kernel<<<total / 256, 256, 0, stream>>>(x, counts, rows, out);
}

// Round 4
// 66.336 us; speedup vs baseline: 1.1818x; 1.1818x over previous
//
#include <hip/hip_runtime.h>

// Gemma4VisionPooler: B=16, S=4096 (64x64 grid), H=1152, OUT=256, k=4.
// out[b,o,:] = (sum over the <=16 rows x[b,s,:] with bucket(s)==o) * sqrt(H)/16
// bucket = (px/k) + (max_x/k)*(py/k); pos clamped >=0; padding rows ([-1,-1]) skipped.

#define BB 16
#define SS 4096
#define HH 1152
#define OUTL 256
#define KK 4
#define K2 16
#define H4 (HH / 4)     // 288 float4 per row
#define HP (H4 / 2)     // 144 threads per output row, 2 rep-strided float4 each

// ---- Prologue: max_x + bucket->rows inverse map; deterministic slots ----
// slot = (py%4)*4 + (px%4): unique per position within a bucket, so lists are
// ordered by construction (no sort). Holes (padding) -> -1, compacted at write.
__global__ __launch_bounds__(256) void build_fused(const int* __restrict__ pos,
                                                   int* __restrict__ counts,
                                                   int* __restrict__ rows) {
    int b = blockIdx.x;
    int t = threadIdx.x;
    const int2* p2 = reinterpret_cast<const int2*>(pos) + (size_t)b * SS;

    // pass 1: max px (padding px=-1 never beats init 0)
    int m = 0;
    for (int s = t; s < SS; s += 256) m = max(m, p2[s].x);
    __shared__ int red[256];
    red[t] = m;
    __syncthreads();
    for (int w = 128; w > 0; w >>= 1) {
        if (t < w) red[t] = max(red[t], red[t + w]);
        __syncthreads();
    }
    __shared__ int smxk;
    if (t == 0) smxk = (red[0] + 1) / KK;

    // pass 2: scatter into LDS at deterministic slots
    __shared__ int lrows[OUTL * K2];
#pragma unroll
    for (int i = 0; i < K2; ++i) lrows[t + i * 256] = -1;
    __syncthreads();
    int mxk = smxk;
    for (int s = t; s < SS; s += 256) {
        int2 xy = p2[s];
        if (xy.x == -1 && xy.y == -1) continue;  // padding row
        int px = max(xy.x, 0), py = max(xy.y, 0);
        int kidx = px / KK + mxk * (py / KK);
        int slot = (py & (KK - 1)) * KK + (px & (KK - 1));
        if ((unsigned)kidx < OUTL) lrows[kidx * K2 + slot] = s;
    }
    __syncthreads();

    // pass 3: thread t owns bucket t — compact valid slots, write count + list
    int* rb = rows + ((size_t)b * OUTL + t) * K2;
    int c = 0;
#pragma unroll
    for (int j = 0; j < K2; ++j) {
        int v = lrows[t * K2 + j];
        if (v >= 0) rb[c++] = v;
    }
    counts[b * OUTL + t] = c;
}

// ---- Heavy gather: 2 rep-strided float4 (32 B) per thread, fully coalesced ----
__global__ __launch_bounds__(256) void gather_kernel(const float* __restrict__ x,
                                                     const int* __restrict__ counts,
                                                     const int* __restrict__ rows,
                                                     float* __restrict__ out) {
    int idx = blockIdx.x * 256 + threadIdx.x;  // [0, B*OUT*HP)
    int c = idx % HP;             // column within rep 0; rep 1 at +HP
    int bo = idx / HP;            // b*OUT + o
    int b = bo >> 8;

    const float4* xb = reinterpret_cast<const float4*>(x) + (size_t)b * SS * H4 + c;
    const int* rl = rows + (size_t)bo * K2;
    int cnt = min(counts[bo], K2);

    float4 a0 = {0.f, 0.f, 0.f, 0.f};
    float4 a1 = {0.f, 0.f, 0.f, 0.f};
    if (cnt == K2) {
        const int4* rl4 = reinterpret_cast<const int4*>(rl);
        int4 ra = rl4[0], rb_ = rl4[1], rc = rl4[2], rd = rl4[3];
        int ridx[K2] = {ra.x, ra.y, ra.z, ra.w, rb_.x, rb_.y, rb_.z, rb_.w,
                        rc.x, rc.y, rc.z, rc.w, rd.x, rd.y, rd.z, rd.w};
#pragma unroll
        for (int j = 0; j < K2; ++j) {
            const float4* p = xb + (size_t)ridx[j] * H4;
            float4 v0 = p[0], v1 = p[HP];
            a0.x += v0.x; a0.y += v0.y; a0.z += v0.z; a0.w += v0.w;
            a1.x += v1.x; a1.y += v1.y; a1.z += v1.z; a1.w += v1.w;
        }
    } else {
        for (int j = 0; j < cnt; ++j) {
            const float4* p = xb + (size_t)rl[j] * H4;
            float4 v0 = p[0], v1 = p[HP];
            a0.x += v0.x; a0.y += v0.y; a0.z += v0.z; a0.w += v0.w;
            a1.x += v1.x; a1.y += v1.y; a1.z += v1.z; a1.w += v1.w;
        }
    }
    const float scale = 2.1213203435596424f;  // sqrt(1152)/16
    a0.x *= scale; a0.y *= scale; a0.z *= scale; a0.w *= scale;
    a1.x *= scale; a1.y *= scale; a1.z *= scale; a1.w *= scale;
    float4* ob = reinterpret_cast<float4*>(out) + (size_t)bo * H4 + c;
    ob[0] = a0;
    ob[HP] = a1;
}

extern "C" void kernel_launch(void* const* d_in, const int* in_sizes, int n_in,
                              void* d_out, int out_size, void* d_ws, size_t ws_size,
                              hipStream_t stream) {
    const float* x = (const float*)d_in[0];
    const int* pos = (const int*)d_in[1];
    float* out = (float*)d_out;

    // ws: counts [B*OUT] ints, rows [B*OUT*K2] ints
    int* counts = (int*)d_ws;
    int* rows = counts + BB * OUTL;

    build_fused<<<BB, 256, 0, stream>>>(pos, counts, rows);

    int total = BB * OUTL * HP;     // 589,824 threads
    gather_kernel<<<total / 256, 256, 0, stream>>>(x, counts, rows, out);
}

// Round 5
// 60.937 us; speedup vs baseline: 1.2865x; 1.0886x over previous
//
#include <hip/hip_runtime.h>

// Gemma4VisionPooler: B=16, S=4096 (64x64 grid), H=1152, OUT=256, k=4.
// out[b,o,:] = (sum over the <=16 rows x[b,s,:] with bucket(s)==o) * sqrt(H)/16
// bucket = (px/k) + (max_x/k)*(py/k); pos clamped >=0; padding rows ([-1,-1])
// contribute zero (reference zeroes them before the segment-sum).
//
// SINGLE fused kernel: each block redundantly rebuilds the bucket->rows map for
// the <=3 output rows it covers, from pos (L2-resident, 32 KB/batch), then
// streams the 16 source rows per output. No prologue kernel, no launch gap.

#define BB 16
#define SS 4096
#define HH 1152
#define OUTL 256
#define KK 4
#define K2 16
#define H4 (HH / 4)     // 288 float4 per row
#define HP (H4 / 2)     // 144 threads per output row, 2 rep-strided float4 each
#define BPB 144         // blocks per batch (144*256 = 256*144 threads = batch outputs)
#define NB 3            // max distinct output rows a 256-thread block can span

__global__ __launch_bounds__(256) void pool_fused(const float* __restrict__ x,
                                                  const int* __restrict__ pos,
                                                  float* __restrict__ out) {
    int blk = blockIdx.x;
    int b = blk / BPB;
    int bl = blk - b * BPB;
    int t = threadIdx.x;
    int lidx = bl * 256 + t;          // [0, 36864) within batch
    int bo_local = lidx / HP;         // output row [0,256)
    int c = lidx - bo_local * HP;     // float4 column [0,144); rep 1 at +HP
    int lo = (bl * 256) / HP;         // first output row this block touches

    const int2* p2 = reinterpret_cast<const int2*>(pos) + (size_t)b * SS;

    // ---- prologue: register-cached scan of this batch's positions ----
    int2 rr[SS / 256];
#pragma unroll
    for (int i = 0; i < SS / 256; ++i) rr[i] = p2[t + i * 256];

    int m = 0;  // max px; padding px=-1 never beats 0
#pragma unroll
    for (int i = 0; i < SS / 256; ++i) m = max(m, rr[i].x);
#pragma unroll
    for (int o = 32; o > 0; o >>= 1) m = max(m, __shfl_down(m, o));

    __shared__ int wred[4];
    __shared__ int lrows[NB * K2];
    if ((t & 63) == 0) wred[t >> 6] = m;
    if (t < NB * K2) lrows[t] = -1;
    __syncthreads();
    int mxk = (max(max(wred[0], wred[1]), max(wred[2], wred[3])) + 1) / KK;

    // deterministic slot = (py%4)*4 + (px%4): lists sorted by construction
#pragma unroll
    for (int i = 0; i < SS / 256; ++i) {
        int2 xy = rr[i];
        if (xy.x == -1 && xy.y == -1) continue;  // padding row -> zero contribution
        int px = max(xy.x, 0), py = max(xy.y, 0);
        int kidx = px / KK + mxk * (py / KK);
        unsigned rel = (unsigned)(kidx - lo);
        if (rel < NB) lrows[rel * K2 + (py & (KK - 1)) * KK + (px & (KK - 1))] = t + i * 256;
    }
    __syncthreads();

    // ---- gather: 16 source rows, 2 rep-strided float4 (32 B) per thread ----
    int rel = bo_local - lo;
    int ridx[K2];
#pragma unroll
    for (int j = 0; j < K2; ++j) ridx[j] = lrows[rel * K2 + j];

    const float4* xb = reinterpret_cast<const float4*>(x) + (size_t)b * SS * H4 + c;
    float4 a0 = {0.f, 0.f, 0.f, 0.f};
    float4 a1 = {0.f, 0.f, 0.f, 0.f};
#pragma unroll
    for (int j = 0; j < K2; ++j) {
        int row = ridx[j];
        if (row >= 0) {
            const float4* p = xb + (size_t)row * H4;
            float4 v0 = p[0], v1 = p[HP];
            a0.x += v0.x; a0.y += v0.y; a0.z += v0.z; a0.w += v0.w;
            a1.x += v1.x; a1.y += v1.y; a1.z += v1.z; a1.w += v1.w;
        }
    }
    const float scale = 2.1213203435596424f;  // sqrt(1152)/16
    a0.x *= scale; a0.y *= scale; a0.z *= scale; a0.w *= scale;
    a1.x *= scale; a1.y *= scale; a1.z *= scale; a1.w *= scale;

    int bo = b * OUTL + bo_local;
    float4* ob = reinterpret_cast<float4*>(out) + (size_t)bo * H4 + c;
    ob[0] = a0;
    ob[HP] = a1;
}

extern "C" void kernel_launch(void* const* d_in, const int* in_sizes, int n_in,
                              void* d_out, int out_size, void* d_ws, size_t ws_size,
                              hipStream_t stream) {
    const float* x = (const float*)d_in[0];
    const int* pos = (const int*)d_in[1];
    float* out = (float*)d_out;

    pool_fused<<<BB * BPB, 256, 0, stream>>>(x, pos, out);  // 2304 blocks
}